// Round 5
// baseline (14.674 us; speedup 1.0000x reference)
//
#include <hip/hip_runtime.h>

#define THREADS 256
#define LPE 16                    // lanes per batch element (12 active qubits)
#define EPB (THREADS / LPE)       // 16 elements per block

// ---------- complex helpers (float2 = {re, im}) ----------
__device__ __forceinline__ float2 cmul(float2 a, float2 b) {
    return make_float2(a.x * b.x - a.y * b.y, a.x * b.y + a.y * b.x);
}
__device__ __forceinline__ float2 cadd(float2 a, float2 b) { return make_float2(a.x + b.x, a.y + b.y); }
__device__ __forceinline__ float2 csub(float2 a, float2 b) { return make_float2(a.x - b.x, a.y - b.y); }
__device__ __forceinline__ float2 conjc(float2 a) { return make_float2(a.x, -a.y); }
__device__ __forceinline__ float2 cmuli(float2 a) { return make_float2(-a.y, a.x); }  // i*a
__device__ __forceinline__ float2 cdot(float2 a, float2 b) {                          // conj(a)*b
    return make_float2(a.x * b.x + a.y * b.y, a.x * b.y - a.y * b.x);
}
__device__ __forceinline__ float2 cscale(float s, float2 a) { return make_float2(s * a.x, s * a.y); }

__device__ __forceinline__ void mat_rx(float c, float s, float2 m[4]) {
    m[0] = make_float2(c, 0.f);  m[1] = make_float2(0.f, -s);
    m[2] = make_float2(0.f, -s); m[3] = make_float2(c, 0.f);
}
__device__ __forceinline__ void mat_ry(float c, float s, float2 m[4]) {
    m[0] = make_float2(c, 0.f);  m[1] = make_float2(-s, 0.f);
    m[2] = make_float2(s, 0.f);  m[3] = make_float2(c, 0.f);
}
__device__ __forceinline__ void mmul(const float2 A[4], const float2 B[4], float2 C[4]) {
    C[0] = cadd(cmul(A[0], B[0]), cmul(A[1], B[2]));
    C[1] = cadd(cmul(A[0], B[1]), cmul(A[1], B[3]));
    C[2] = cadd(cmul(A[2], B[0]), cmul(A[3], B[2]));
    C[3] = cadd(cmul(A[2], B[1]), cmul(A[3], B[3]));
}

__device__ __forceinline__ float2 shfl2(float2 a, int src) {
    return make_float2(__shfl(a.x, src), __shfl(a.y, src));
}
__device__ __forceinline__ float2 shflx2(float2 a, int mask) {
    return make_float2(__shfl_xor(a.x, mask), __shfl_xor(a.y, mask));
}

// Closed-form evaluation (math identical to rounds 2-4), ONE QUBIT PER LANE.
// 16-lane group per batch element; lane sub = qubit q (sub 12..15 idle).
//   u_q = (RX RY RX)|0>, V_q = RY RX RY from qubit q's 3 conv angles.
//   Factor at t = 11-q (q>=1): h^v_t = V_q * (u_{q-1} twisted by i^[b!=v]);
//   S_t[v][vp] = <h^v_t, h^vp_t>.  P0 = prod_{t!=10} S_t, P1 = prod_{t!=9} S_t
//   via 4-round __shfl_xor butterfly product (identity on masked slots).
//   h10 (lane1), h9 (lane2), V0 (lane0), u11 (lane11) -> lane0 evaluates
//   <O_w>, O = (RY RX)^dag Z (RY RX) twisted by diag(i) per w, writes float2.
__global__ __launch_bounds__(THREADS) void qcnn_closed16(
    const float* __restrict__ x,      // [B,1,14,14]
    const float* __restrict__ cw,     // [1,1,4,4]
    const float* __restrict__ cb,     // [1]
    const float* __restrict__ th,     // [3]
    float* __restrict__ out,          // [B,2]
    int B)
{
    __shared__ float xs[EPB][197];

    const int tid = threadIdx.x;
    const int sub = tid & (LPE - 1);
    const int grp = tid >> 4;
    const int b   = blockIdx.x * EPB + grp;

    // ---- coalesced staging: EPB*196 floats = 784 float4 ----
    {
        const float4* xv = (const float4*)(x + (size_t)blockIdx.x * EPB * 196);
#pragma unroll
        for (int k = 0; k < 4; ++k) {
            int i4 = tid + k * THREADS;
            if (i4 < (EPB * 196) / 4) {
                float4 v = xv[i4];
                int r = i4 / 49;                  // 49 float4 per row
                int c = (i4 - r * 49) * 4;
                xs[r][c + 0] = v.x;
                xs[r][c + 1] = v.y;
                xs[r][c + 2] = v.z;
                xs[r][c + 3] = v.w;
            }
        }
    }
    __syncthreads();

    // ---- conv weights ----
    float wgt[16];
#pragma unroll
    for (int k = 0; k < 16; ++k) wgt[k] = cw[k];
    const float bias = cb[0];
    const float* row = xs[grp];

    // ---- this lane's qubit: 3 conv outputs (idle lanes clamp to q=0) ----
    const int q = (sub < 12) ? sub : 0;
    float ang[3];
#pragma unroll
    for (int m = 0; m < 3; ++m) {
        int o  = 3 * q + m;
        int oy = o / 6, ox = o % 6;
        float acc = bias;
#pragma unroll
        for (int ky = 0; ky < 4; ++ky)
#pragma unroll
            for (int kx = 0; kx < 4; ++kx)
                acc += row[(2 * oy + ky) * 14 + (2 * ox + kx)] * wgt[ky * 4 + kx];
        ang[m] = acc;
    }

    float c0 = __cosf(0.5f * ang[0]), s0 = __sinf(0.5f * ang[0]);
    float c1 = __cosf(0.5f * ang[1]), s1 = __sinf(0.5f * ang[1]);
    float c2 = __cosf(0.5f * ang[2]), s2 = __sinf(0.5f * ang[2]);

    // u_q = RX(a2) RY(a1) RX(a0) |0>
    float2 uq[2];
    {
        float2 b0c = make_float2(c0, 0.f);
        float2 b1c = make_float2(0.f, -s0);
        float2 t0 = csub(cscale(c1, b0c), cscale(s1, b1c));
        float2 t1 = cadd(cscale(s1, b0c), cscale(c1, b1c));
        uq[0] = cadd(cscale(c2, t0), cmul(make_float2(0.f, -s2), t1));
        uq[1] = cadd(cmul(make_float2(0.f, -s2), t0), cscale(c2, t1));
    }
    // V_q = RY(a2) RX(a1) RY(a0)
    float2 Vq[4];
    {
        float2 A[4], Bm[4], Cm[4], T[4];
        mat_ry(c0, s0, A); mat_rx(c1, s1, Bm); mat_ry(c2, s2, Cm);
        mmul(Bm, A, T); mmul(Cm, T, Vq);
    }

    // ---- u_{q-1} from the previous lane ----
    const int srcPrev = (sub == 0) ? tid : tid - 1;
    float2 up0 = shfl2(uq[0], srcPrev);
    float2 up1 = shfl2(uq[1], srcPrev);

    // ---- factor h^v_t and S_t ----
    float2 hc[2][2];
#pragma unroll
    for (int v = 0; v < 2; ++v) {
        float2 g0 = (v == 0) ? up0 : cmuli(up0);
        float2 g1 = (v == 1) ? up1 : cmuli(up1);
        hc[v][0] = cadd(cmul(Vq[0], g0), cmul(Vq[1], g1));
        hc[v][1] = cadd(cmul(Vq[2], g0), cmul(Vq[3], g1));
    }
    float2 S[2][2];
#pragma unroll
    for (int v = 0; v < 2; ++v)
#pragma unroll
        for (int vp = 0; vp < 2; ++vp)
            S[v][vp] = cadd(cdot(hc[v][0], hc[vp][0]),
                            cdot(hc[v][1], hc[vp][1]));

    // ---- butterfly product of S over the 16-lane group (masked slots = I) ----
    const bool act = (sub >= 1 && sub <= 11);
    const int  t   = 11 - sub;
    const float2 one = make_float2(1.f, 0.f);
    float2 P0[2][2], P1[2][2];
#pragma unroll
    for (int v = 0; v < 2; ++v)
#pragma unroll
        for (int vp = 0; vp < 2; ++vp) {
            P0[v][vp] = (act && t != 10) ? S[v][vp] : one;
            P1[v][vp] = (act && t != 9)  ? S[v][vp] : one;
        }
#pragma unroll
    for (int d = 1; d <= 8; d <<= 1) {
#pragma unroll
        for (int v = 0; v < 2; ++v)
#pragma unroll
            for (int vp = 0; vp < 2; ++vp) {
                P0[v][vp] = cmul(P0[v][vp], shflx2(P0[v][vp], d));
                P1[v][vp] = cmul(P1[v][vp], shflx2(P1[v][vp], d));
            }
    }

    // ---- gather h10 (lane1), h9 (lane2), V0 (lane0), u11 (lane11) ----
    const int base = tid & ~(LPE - 1);
    float2 h10[2][2], h9[2][2];
#pragma unroll
    for (int v = 0; v < 2; ++v)
#pragma unroll
        for (int bb = 0; bb < 2; ++bb) {
            h10[v][bb] = shfl2(hc[v][bb], base + 1);
            h9[v][bb]  = shfl2(hc[v][bb], base + 2);
        }
    float2 u11_0 = shfl2(uq[0], base + 11);
    float2 u11_1 = shfl2(uq[1], base + 11);
    float2 V0[4];
#pragma unroll
    for (int k = 0; k < 4; ++k) V0[k] = shfl2(Vq[k], base);

    // ---- final evaluation on lane 0 of each group ----
    if (sub == 0) {
        float2 h11[2][2];
        h11[0][0] = cmul(u11_0, V0[0]); h11[0][1] = cmul(u11_0, V0[2]);
        h11[1][0] = cmul(u11_1, V0[1]); h11[1][1] = cmul(u11_1, V0[3]);

        // observable O = (RY(t1) RX(t0))^dag Z (RY(t1) RX(t0))
        float ct0 = __cosf(0.5f * th[0]), st0 = __sinf(0.5f * th[0]);
        float ct1 = __cosf(0.5f * th[1]), st1 = __sinf(0.5f * th[1]);
        float2 Rx[4], Ry[4], M[4];
        mat_rx(ct0, st0, Rx); mat_ry(ct1, st1, Ry); mmul(Ry, Rx, M);
        const float  o00 = (M[0].x * M[0].x + M[0].y * M[0].y)
                         - (M[2].x * M[2].x + M[2].y * M[2].y);
        const float2 o01 = csub(cmul(conjc(M[0]), M[1]), cmul(conjc(M[2]), M[3]));

        float2 E0 = make_float2(0.f, 0.f), E1 = make_float2(0.f, 0.f);
#pragma unroll
        for (int w = 0; w < 2; ++w) {
            float2 Ow01 = (w == 0) ? cmuli(o01) : make_float2(o01.y, -o01.x);
            float2 Ow10 = conjc(Ow01);
#pragma unroll
            for (int v = 0; v < 2; ++v) {
#pragma unroll
                for (int vp = 0; vp < 2; ++vp) {
                    float2 A = cdot(h11[v][w], h11[vp][w]);
                    float2 T0 = cadd(cadd(
                        cscale(o00, csub(cdot(h10[v][0], h10[vp][0]),
                                         cdot(h10[v][1], h10[vp][1]))),
                        cmul(Ow01, cdot(h10[v][0], h10[vp][1]))),
                        cmul(Ow10, cdot(h10[v][1], h10[vp][0])));
                    float2 T1 = cadd(cadd(
                        cscale(o00, csub(cdot(h9[v][0], h9[vp][0]),
                                         cdot(h9[v][1], h9[vp][1]))),
                        cmul(Ow01, cdot(h9[v][0], h9[vp][1]))),
                        cmul(Ow10, cdot(h9[v][1], h9[vp][0])));
                    E0 = cadd(E0, cmul(cmul(A, T0), P0[v][vp]));
                    E1 = cadd(E1, cmul(cmul(A, T1), P1[v][vp]));
                }
            }
        }
        if (b < B)
            ((float2*)out)[b] = make_float2(E0.x, E1.x);
    }
}

extern "C" void kernel_launch(void* const* d_in, const int* in_sizes, int n_in,
                              void* d_out, int out_size, void* d_ws, size_t ws_size,
                              hipStream_t stream) {
    const float* x  = (const float*)d_in[0];
    const float* cw = (const float*)d_in[1];
    const float* cb = (const float*)d_in[2];
    const float* th = (const float*)d_in[3];
    float* out = (float*)d_out;
    int B = in_sizes[0] / 196;                    // 4096, divisible by EPB
    qcnn_closed16<<<B / EPB, THREADS, 0, stream>>>(x, cw, cb, th, out, B);
}

// Round 6
// 11.011 us; speedup vs baseline: 1.3327x; 1.3327x over previous
//
#include <hip/hip_runtime.h>

#define THREADS 64
#define EPB 16      // batch elements per block (4 lanes per element)

// ---------- complex helpers (float2 = {re, im}) ----------
__device__ __forceinline__ float2 cmul(float2 a, float2 b) {
    return make_float2(a.x * b.x - a.y * b.y, a.x * b.y + a.y * b.x);
}
__device__ __forceinline__ float2 cadd(float2 a, float2 b) { return make_float2(a.x + b.x, a.y + b.y); }
__device__ __forceinline__ float2 csub(float2 a, float2 b) { return make_float2(a.x - b.x, a.y - b.y); }
__device__ __forceinline__ float2 conjc(float2 a) { return make_float2(a.x, -a.y); }
__device__ __forceinline__ float2 cmuli(float2 a) { return make_float2(-a.y, a.x); }  // i*a
__device__ __forceinline__ float2 cdot(float2 a, float2 b) {                          // conj(a)*b
    return make_float2(a.x * b.x + a.y * b.y, a.x * b.y - a.y * b.x);
}
__device__ __forceinline__ float2 cscale(float s, float2 a) { return make_float2(s * a.x, s * a.y); }

__device__ __forceinline__ void mat_rx(float c, float s, float2 m[4]) {
    m[0] = make_float2(c, 0.f);  m[1] = make_float2(0.f, -s);
    m[2] = make_float2(0.f, -s); m[3] = make_float2(c, 0.f);
}
__device__ __forceinline__ void mat_ry(float c, float s, float2 m[4]) {
    m[0] = make_float2(c, 0.f);  m[1] = make_float2(-s, 0.f);
    m[2] = make_float2(s, 0.f);  m[3] = make_float2(c, 0.f);
}
__device__ __forceinline__ void mmul(const float2 A[4], const float2 B[4], float2 C[4]) {
    C[0] = cadd(cmul(A[0], B[0]), cmul(A[1], B[2]));
    C[1] = cadd(cmul(A[0], B[1]), cmul(A[1], B[3]));
    C[2] = cadd(cmul(A[2], B[0]), cmul(A[3], B[2]));
    C[3] = cadd(cmul(A[2], B[1]), cmul(A[3], B[3]));
}

__device__ __forceinline__ float2 shfl2(float2 a, int src) {
    return make_float2(__shfl(a.x, src), __shfl(a.y, src));
}
__device__ __forceinline__ float2 shflx2(float2 a, int mask) {
    return make_float2(__shfl_xor(a.x, mask), __shfl_xor(a.y, mask));
}

// Closed-form evaluation (math identical to rounds 2-4), 4 lanes per batch
// element: lane sub owns qubits q = 3*sub .. 3*sub+2. See round-4 comments.
// Round-6 deltas vs round 4: observable (batch-uniform) hoisted to the top so
// its trig/loads hide under the conv; branch-free float4 staging.
__global__ __launch_bounds__(THREADS) void qcnn_closed4(
    const float* __restrict__ x,      // [B,1,14,14]
    const float* __restrict__ cw,     // [1,1,4,4]
    const float* __restrict__ cb,     // [1]
    const float* __restrict__ th,     // [3]
    float* __restrict__ out,          // [B,2]
    int B)
{
    __shared__ float xs[EPB][197];

    const int tid = threadIdx.x;
    const int sub = tid & 3;          // which qubit-triplet of the element
    const int grp = tid >> 2;         // element within block
    const int b   = blockIdx.x * EPB + grp;

    // ---- issue observable-parameter loads early ----
    const float th0 = th[0], th1 = th[1];

    // ---- coalesced staging: 16*196 floats = 784 float4, branch-free ----
    {
        const float4* xv = (const float4*)(x + (size_t)blockIdx.x * EPB * 196);
        float4 v[12];
#pragma unroll
        for (int k = 0; k < 12; ++k) v[k] = xv[tid + k * THREADS];
        float4 vt;
        if (tid < 16) vt = xv[768 + tid];
#pragma unroll
        for (int k = 0; k < 12; ++k) {
            int i4 = tid + k * THREADS;
            int r  = i4 / 49;                  // 49 float4 per row
            int c  = (i4 - r * 49) * 4;
            xs[r][c + 0] = v[k].x;
            xs[r][c + 1] = v[k].y;
            xs[r][c + 2] = v[k].z;
            xs[r][c + 3] = v[k].w;
        }
        if (tid < 16) {
            int i4 = 768 + tid;
            int r  = i4 / 49;
            int c  = (i4 - r * 49) * 4;
            xs[r][c + 0] = vt.x;
            xs[r][c + 1] = vt.y;
            xs[r][c + 2] = vt.z;
            xs[r][c + 3] = vt.w;
        }
    }

    // ---- observable O = (RY(t1) RX(t0))^dag Z (RY(t1) RX(t0)) — uniform,
    //      computed on all lanes while the LDS staging drains ----
    float o00; float2 o01;
    {
        float ct0 = __cosf(0.5f * th0), st0v = __sinf(0.5f * th0);
        float ct1 = __cosf(0.5f * th1), st1v = __sinf(0.5f * th1);
        float2 Rx[4], Ry[4], M[4];
        mat_rx(ct0, st0v, Rx); mat_ry(ct1, st1v, Ry); mmul(Ry, Rx, M);
        o00 = (M[0].x * M[0].x + M[0].y * M[0].y)
            - (M[2].x * M[2].x + M[2].y * M[2].y);
        o01 = csub(cmul(conjc(M[0]), M[1]), cmul(conjc(M[2]), M[3]));
    }

    // ---- conv weights (uniform -> scalar regs) ----
    float wgt[16];
#pragma unroll
    for (int k = 0; k < 16; ++k) wgt[k] = cw[k];
    const float bias = cb[0];

    __syncthreads();
    const float* row = xs[grp];

    // ---- 9 conv outputs for this lane: flat o = sub*9 + m ----
    float ang[9];
#pragma unroll
    for (int m = 0; m < 9; ++m) {
        int o  = sub * 9 + m;
        int oy = o / 6, ox = o % 6;
        float acc = bias;
#pragma unroll
        for (int ky = 0; ky < 4; ++ky)
#pragma unroll
            for (int kx = 0; kx < 4; ++kx)
                acc += row[(2 * oy + ky) * 14 + (2 * ox + kx)] * wgt[ky * 4 + kx];
        ang[m] = acc;
    }

    // ---- per-owned-qubit u and V ----
    float2 u[3][2];
    float2 V[3][4];
#pragma unroll
    for (int j = 0; j < 3; ++j) {
        float c0 = __cosf(0.5f * ang[3 * j + 0]), s0 = __sinf(0.5f * ang[3 * j + 0]);
        float c1 = __cosf(0.5f * ang[3 * j + 1]), s1 = __sinf(0.5f * ang[3 * j + 1]);
        float c2 = __cosf(0.5f * ang[3 * j + 2]), s2 = __sinf(0.5f * ang[3 * j + 2]);
        // u = RX(a2) RY(a1) RX(a0) |0>
        {
            float2 b0c = make_float2(c0, 0.f);
            float2 b1c = make_float2(0.f, -s0);
            float2 t0 = csub(cscale(c1, b0c), cscale(s1, b1c));
            float2 t1 = cadd(cscale(s1, b0c), cscale(c1, b1c));
            u[j][0] = cadd(cscale(c2, t0), cmul(make_float2(0.f, -s2), t1));
            u[j][1] = cadd(cmul(make_float2(0.f, -s2), t0), cscale(c2, t1));
        }
        // V = RY(a2) RX(a1) RY(a0)
        {
            float2 A[4], Bm[4], Cm[4], T[4];
            mat_ry(c0, s0, A); mat_rx(c1, s1, Bm); mat_ry(c2, s2, Cm);
            mmul(Bm, A, T); mmul(Cm, T, V[j]);
        }
    }

    // ---- u of previous lane's last qubit (u_{3*sub-1}) ----
    const int srcPrev = tid - (sub ? 1 : 0);     // sub==0: self (unused)
    float2 up0 = shfl2(u[2][0], srcPrev);
    float2 up1 = shfl2(u[2][1], srcPrev);

    // ---- factors, retained h's, partial products ----
    float2 P0p[2][2], P1p[2][2];
#pragma unroll
    for (int v = 0; v < 2; ++v)
#pragma unroll
        for (int vp = 0; vp < 2; ++vp) {
            P0p[v][vp] = make_float2(1.f, 0.f);
            P1p[v][vp] = make_float2(1.f, 0.f);
        }
    float2 V0[4], h9[2][2], h10[2][2];

#pragma unroll
    for (int j = 0; j < 3; ++j) {
        float2 pv0 = (j == 0) ? up0 : u[j - 1][0];
        float2 pv1 = (j == 0) ? up1 : u[j - 1][1];
        float2 hc[2][2];
#pragma unroll
        for (int v = 0; v < 2; ++v) {
            float2 g0 = (v == 0) ? pv0 : cmuli(pv0);
            float2 g1 = (v == 1) ? pv1 : cmuli(pv1);
            hc[v][0] = cadd(cmul(V[j][0], g0), cmul(V[j][1], g1));
            hc[v][1] = cadd(cmul(V[j][2], g0), cmul(V[j][3], g1));
        }
        float2 S[2][2];
#pragma unroll
        for (int v = 0; v < 2; ++v)
#pragma unroll
            for (int vp = 0; vp < 2; ++vp)
                S[v][vp] = cadd(cdot(hc[v][0], hc[vp][0]),
                                cdot(hc[v][1], hc[vp][1]));

        if (sub == 0) {
            if (j == 0) {
#pragma unroll
                for (int k = 0; k < 4; ++k) V0[k] = V[0][k];
            } else if (j == 1) {            // q=1 -> t=10: in P1 only
#pragma unroll
                for (int v = 0; v < 2; ++v) {
                    h10[v][0] = hc[v][0]; h10[v][1] = hc[v][1];
#pragma unroll
                    for (int vp = 0; vp < 2; ++vp)
                        P1p[v][vp] = cmul(P1p[v][vp], S[v][vp]);
                }
            } else {                        // q=2 -> t=9: in P0 only
#pragma unroll
                for (int v = 0; v < 2; ++v) {
                    h9[v][0] = hc[v][0]; h9[v][1] = hc[v][1];
#pragma unroll
                    for (int vp = 0; vp < 2; ++vp)
                        P0p[v][vp] = cmul(P0p[v][vp], S[v][vp]);
                }
            }
        } else {
#pragma unroll
            for (int v = 0; v < 2; ++v)
#pragma unroll
                for (int vp = 0; vp < 2; ++vp) {
                    P0p[v][vp] = cmul(P0p[v][vp], S[v][vp]);
                    P1p[v][vp] = cmul(P1p[v][vp], S[v][vp]);
                }
        }
    }

    // ---- combine partial products across the 4 lanes of the group ----
#pragma unroll
    for (int d = 1; d <= 2; d <<= 1) {
#pragma unroll
        for (int v = 0; v < 2; ++v)
#pragma unroll
            for (int vp = 0; vp < 2; ++vp) {
                P0p[v][vp] = cmul(P0p[v][vp], shflx2(P0p[v][vp], d));
                P1p[v][vp] = cmul(P1p[v][vp], shflx2(P1p[v][vp], d));
            }
    }

    // ---- u_11 (lane sub=3's last u) to everyone in the group ----
    const int srcLast = tid | 3;
    float2 u11_0 = shfl2(u[2][0], srcLast);
    float2 u11_1 = shfl2(u[2][1], srcLast);

    if (sub == 0) {
        float2 h11[2][2];
        h11[0][0] = cmul(u11_0, V0[0]); h11[0][1] = cmul(u11_0, V0[2]);
        h11[1][0] = cmul(u11_1, V0[1]); h11[1][1] = cmul(u11_1, V0[3]);

        float2 E0 = make_float2(0.f, 0.f), E1 = make_float2(0.f, 0.f);
#pragma unroll
        for (int w = 0; w < 2; ++w) {
            float2 Ow01 = (w == 0) ? cmuli(o01) : make_float2(o01.y, -o01.x);
            float2 Ow10 = conjc(Ow01);
#pragma unroll
            for (int v = 0; v < 2; ++v) {
#pragma unroll
                for (int vp = 0; vp < 2; ++vp) {
                    float2 A = cdot(h11[v][w], h11[vp][w]);
                    float2 T0 = cadd(cadd(
                        cscale(o00, csub(cdot(h10[v][0], h10[vp][0]),
                                         cdot(h10[v][1], h10[vp][1]))),
                        cmul(Ow01, cdot(h10[v][0], h10[vp][1]))),
                        cmul(Ow10, cdot(h10[v][1], h10[vp][0])));
                    float2 T1 = cadd(cadd(
                        cscale(o00, csub(cdot(h9[v][0], h9[vp][0]),
                                         cdot(h9[v][1], h9[vp][1]))),
                        cmul(Ow01, cdot(h9[v][0], h9[vp][1]))),
                        cmul(Ow10, cdot(h9[v][1], h9[vp][0])));
                    E0 = cadd(E0, cmul(cmul(A, T0), P0p[v][vp]));
                    E1 = cadd(E1, cmul(cmul(A, T1), P1p[v][vp]));
                }
            }
        }
        if (b < B)
            ((float2*)out)[b] = make_float2(E0.x, E1.x);
    }
}

extern "C" void kernel_launch(void* const* d_in, const int* in_sizes, int n_in,
                              void* d_out, int out_size, void* d_ws, size_t ws_size,
                              hipStream_t stream) {
    const float* x  = (const float*)d_in[0];
    const float* cw = (const float*)d_in[1];
    const float* cb = (const float*)d_in[2];
    const float* th = (const float*)d_in[3];
    float* out = (float*)d_out;
    int B = in_sizes[0] / 196;                 // 4096, divisible by EPB
    qcnn_closed4<<<B / EPB, THREADS, 0, stream>>>(x, cw, cb, th, out, B);
}

// Round 7
// 10.111 us; speedup vs baseline: 1.4513x; 1.0890x over previous
//
#include <hip/hip_runtime.h>

#define THREADS 64
#define EPB 16      // batch elements per block (4 lanes per element)

// ---------- complex helpers (float2 = {re, im}) ----------
__device__ __forceinline__ float2 cmul(float2 a, float2 b) {
    return make_float2(a.x * b.x - a.y * b.y, a.x * b.y + a.y * b.x);
}
__device__ __forceinline__ float2 cadd(float2 a, float2 b) { return make_float2(a.x + b.x, a.y + b.y); }
__device__ __forceinline__ float2 csub(float2 a, float2 b) { return make_float2(a.x - b.x, a.y - b.y); }
__device__ __forceinline__ float2 conjc(float2 a) { return make_float2(a.x, -a.y); }
__device__ __forceinline__ float2 cmuli(float2 a) { return make_float2(-a.y, a.x); }  // i*a
__device__ __forceinline__ float2 cdot(float2 a, float2 b) {                          // conj(a)*b
    return make_float2(a.x * b.x + a.y * b.y, a.x * b.y - a.y * b.x);
}
__device__ __forceinline__ float2 cscale(float s, float2 a) { return make_float2(s * a.x, s * a.y); }

__device__ __forceinline__ void mat_rx(float c, float s, float2 m[4]) {
    m[0] = make_float2(c, 0.f);  m[1] = make_float2(0.f, -s);
    m[2] = make_float2(0.f, -s); m[3] = make_float2(c, 0.f);
}
__device__ __forceinline__ void mat_ry(float c, float s, float2 m[4]) {
    m[0] = make_float2(c, 0.f);  m[1] = make_float2(-s, 0.f);
    m[2] = make_float2(s, 0.f);  m[3] = make_float2(c, 0.f);
}
__device__ __forceinline__ void mmul(const float2 A[4], const float2 B[4], float2 C[4]) {
    C[0] = cadd(cmul(A[0], B[0]), cmul(A[1], B[2]));
    C[1] = cadd(cmul(A[0], B[1]), cmul(A[1], B[3]));
    C[2] = cadd(cmul(A[2], B[0]), cmul(A[3], B[2]));
    C[3] = cadd(cmul(A[2], B[1]), cmul(A[3], B[3]));
}

__device__ __forceinline__ float2 shfl2(float2 a, int src) {
    return make_float2(__shfl(a.x, src), __shfl(a.y, src));
}
__device__ __forceinline__ float2 shflx2(float2 a, int mask) {
    return make_float2(__shfl_xor(a.x, mask), __shfl_xor(a.y, mask));
}

// Closed-form evaluation (math identical to rounds 2-6), 4 lanes per batch
// element: lane sub owns qubits q = 3*sub .. 3*sub+2.
// Round-7 delta: NO LDS. Each lane loads its 6 needed input rows (84 floats,
// 21 aligned float4, base offset r0*14 with r0 = {0,2,6,8}[sub]) directly to
// registers. Conv computed over unified mm = m + 3*(sub&1) in 0..11 so all
// register indices are compile-time; ang[m] selected by sub parity.
__global__ __launch_bounds__(THREADS) void qcnn_closed4(
    const float* __restrict__ x,      // [B,1,14,14]
    const float* __restrict__ cw,     // [1,1,4,4]
    const float* __restrict__ cb,     // [1]
    const float* __restrict__ th,     // [3]
    float* __restrict__ out,          // [B,2]
    int B)
{
    const int tid = threadIdx.x;
    const int sub = tid & 3;          // which qubit-triplet of the element
    const int grp = tid >> 2;         // element within block
    const int b   = blockIdx.x * EPB + grp;

    // ---- direct register load: 6 rows = 84 floats = 21 float4 ----
    const int r0 = (sub * 3) & ~1;    // first needed row: {0,2,6,8}
    const float* src = x + (size_t)b * 196 + r0 * 14;
    float arr[84];
    {
        const float4* sv = (const float4*)src;   // 16B-aligned: r0*14 % 4 == 0
#pragma unroll
        for (int k = 0; k < 21; ++k) {
            float4 v = sv[k];
            arr[4 * k + 0] = v.x;
            arr[4 * k + 1] = v.y;
            arr[4 * k + 2] = v.z;
            arr[4 * k + 3] = v.w;
        }
    }

    // ---- observable O = (RY(t1) RX(t0))^dag Z (RY(t1) RX(t0)) — uniform,
    //      computed while the input loads are in flight ----
    const float th0 = th[0], th1 = th[1];
    float o00; float2 o01;
    {
        float ct0 = __cosf(0.5f * th0), st0v = __sinf(0.5f * th0);
        float ct1 = __cosf(0.5f * th1), st1v = __sinf(0.5f * th1);
        float2 Rx[4], Ry[4], M[4];
        mat_rx(ct0, st0v, Rx); mat_ry(ct1, st1v, Ry); mmul(Ry, Rx, M);
        o00 = (M[0].x * M[0].x + M[0].y * M[0].y)
            - (M[2].x * M[2].x + M[2].y * M[2].y);
        o01 = csub(cmul(conjc(M[0]), M[1]), cmul(conjc(M[2]), M[3]));
    }

    // ---- conv weights (uniform) ----
    float wgt[16];
#pragma unroll
    for (int k = 0; k < 16; ++k) wgt[k] = cw[k];
    const float bias = cb[0];

    // ---- 12 conv outputs over unified window (static indices) ----
    // cv[mm]: relative row 2*(mm/6)+ky, col 2*(mm%6)+kx within arr[6][14].
    float cv[12];
#pragma unroll
    for (int mm = 0; mm < 12; ++mm) {
        const int ry = 2 * (mm / 6), cxx = 2 * (mm % 6);
        float acc = bias;
#pragma unroll
        for (int ky = 0; ky < 4; ++ky)
#pragma unroll
            for (int kx = 0; kx < 4; ++kx)
                acc += arr[(ry + ky) * 14 + cxx + kx] * wgt[ky * 4 + kx];
        cv[mm] = acc;
    }
    // ang[m] = cv[m + 3*(sub&1)]
    const bool oddsub = (sub & 1);
    float ang[9];
#pragma unroll
    for (int m = 0; m < 9; ++m)
        ang[m] = oddsub ? cv[m + 3] : cv[m];

    // ---- per-owned-qubit u and V ----
    float2 u[3][2];
    float2 V[3][4];
#pragma unroll
    for (int j = 0; j < 3; ++j) {
        float c0 = __cosf(0.5f * ang[3 * j + 0]), s0 = __sinf(0.5f * ang[3 * j + 0]);
        float c1 = __cosf(0.5f * ang[3 * j + 1]), s1 = __sinf(0.5f * ang[3 * j + 1]);
        float c2 = __cosf(0.5f * ang[3 * j + 2]), s2 = __sinf(0.5f * ang[3 * j + 2]);
        // u = RX(a2) RY(a1) RX(a0) |0>
        {
            float2 b0c = make_float2(c0, 0.f);
            float2 b1c = make_float2(0.f, -s0);
            float2 t0 = csub(cscale(c1, b0c), cscale(s1, b1c));
            float2 t1 = cadd(cscale(s1, b0c), cscale(c1, b1c));
            u[j][0] = cadd(cscale(c2, t0), cmul(make_float2(0.f, -s2), t1));
            u[j][1] = cadd(cmul(make_float2(0.f, -s2), t0), cscale(c2, t1));
        }
        // V = RY(a2) RX(a1) RY(a0)
        {
            float2 A[4], Bm[4], Cm[4], T[4];
            mat_ry(c0, s0, A); mat_rx(c1, s1, Bm); mat_ry(c2, s2, Cm);
            mmul(Bm, A, T); mmul(Cm, T, V[j]);
        }
    }

    // ---- u of previous lane's last qubit (u_{3*sub-1}) ----
    const int srcPrev = tid - (sub ? 1 : 0);     // sub==0: self (unused)
    float2 up0 = shfl2(u[2][0], srcPrev);
    float2 up1 = shfl2(u[2][1], srcPrev);

    // ---- factors, retained h's, partial products ----
    float2 P0p[2][2], P1p[2][2];
#pragma unroll
    for (int v = 0; v < 2; ++v)
#pragma unroll
        for (int vp = 0; vp < 2; ++vp) {
            P0p[v][vp] = make_float2(1.f, 0.f);
            P1p[v][vp] = make_float2(1.f, 0.f);
        }
    float2 V0[4], h9[2][2], h10[2][2];

#pragma unroll
    for (int j = 0; j < 3; ++j) {
        float2 pv0 = (j == 0) ? up0 : u[j - 1][0];
        float2 pv1 = (j == 0) ? up1 : u[j - 1][1];
        float2 hc[2][2];
#pragma unroll
        for (int v = 0; v < 2; ++v) {
            float2 g0 = (v == 0) ? pv0 : cmuli(pv0);
            float2 g1 = (v == 1) ? pv1 : cmuli(pv1);
            hc[v][0] = cadd(cmul(V[j][0], g0), cmul(V[j][1], g1));
            hc[v][1] = cadd(cmul(V[j][2], g0), cmul(V[j][3], g1));
        }
        float2 S[2][2];
#pragma unroll
        for (int v = 0; v < 2; ++v)
#pragma unroll
            for (int vp = 0; vp < 2; ++vp)
                S[v][vp] = cadd(cdot(hc[v][0], hc[vp][0]),
                                cdot(hc[v][1], hc[vp][1]));

        if (sub == 0) {
            if (j == 0) {
#pragma unroll
                for (int k = 0; k < 4; ++k) V0[k] = V[0][k];
            } else if (j == 1) {            // q=1 -> t=10: in P1 only
#pragma unroll
                for (int v = 0; v < 2; ++v) {
                    h10[v][0] = hc[v][0]; h10[v][1] = hc[v][1];
#pragma unroll
                    for (int vp = 0; vp < 2; ++vp)
                        P1p[v][vp] = cmul(P1p[v][vp], S[v][vp]);
                }
            } else {                        // q=2 -> t=9: in P0 only
#pragma unroll
                for (int v = 0; v < 2; ++v) {
                    h9[v][0] = hc[v][0]; h9[v][1] = hc[v][1];
#pragma unroll
                    for (int vp = 0; vp < 2; ++vp)
                        P0p[v][vp] = cmul(P0p[v][vp], S[v][vp]);
                }
            }
        } else {
#pragma unroll
            for (int v = 0; v < 2; ++v)
#pragma unroll
                for (int vp = 0; vp < 2; ++vp) {
                    P0p[v][vp] = cmul(P0p[v][vp], S[v][vp]);
                    P1p[v][vp] = cmul(P1p[v][vp], S[v][vp]);
                }
        }
    }

    // ---- combine partial products across the 4 lanes of the group ----
#pragma unroll
    for (int d = 1; d <= 2; d <<= 1) {
#pragma unroll
        for (int v = 0; v < 2; ++v)
#pragma unroll
            for (int vp = 0; vp < 2; ++vp) {
                P0p[v][vp] = cmul(P0p[v][vp], shflx2(P0p[v][vp], d));
                P1p[v][vp] = cmul(P1p[v][vp], shflx2(P1p[v][vp], d));
            }
    }

    // ---- u_11 (lane sub=3's last u) to everyone in the group ----
    const int srcLast = tid | 3;
    float2 u11_0 = shfl2(u[2][0], srcLast);
    float2 u11_1 = shfl2(u[2][1], srcLast);

    if (sub == 0) {
        float2 h11[2][2];
        h11[0][0] = cmul(u11_0, V0[0]); h11[0][1] = cmul(u11_0, V0[2]);
        h11[1][0] = cmul(u11_1, V0[1]); h11[1][1] = cmul(u11_1, V0[3]);

        float2 E0 = make_float2(0.f, 0.f), E1 = make_float2(0.f, 0.f);
#pragma unroll
        for (int w = 0; w < 2; ++w) {
            float2 Ow01 = (w == 0) ? cmuli(o01) : make_float2(o01.y, -o01.x);
            float2 Ow10 = conjc(Ow01);
#pragma unroll
            for (int v = 0; v < 2; ++v) {
#pragma unroll
                for (int vp = 0; vp < 2; ++vp) {
                    float2 A = cdot(h11[v][w], h11[vp][w]);
                    float2 T0 = cadd(cadd(
                        cscale(o00, csub(cdot(h10[v][0], h10[vp][0]),
                                         cdot(h10[v][1], h10[vp][1]))),
                        cmul(Ow01, cdot(h10[v][0], h10[vp][1]))),
                        cmul(Ow10, cdot(h10[v][1], h10[vp][0])));
                    float2 T1 = cadd(cadd(
                        cscale(o00, csub(cdot(h9[v][0], h9[vp][0]),
                                         cdot(h9[v][1], h9[vp][1]))),
                        cmul(Ow01, cdot(h9[v][0], h9[vp][1]))),
                        cmul(Ow10, cdot(h9[v][1], h9[vp][0])));
                    E0 = cadd(E0, cmul(cmul(A, T0), P0p[v][vp]));
                    E1 = cadd(E1, cmul(cmul(A, T1), P1p[v][vp]));
                }
            }
        }
        if (b < B)
            ((float2*)out)[b] = make_float2(E0.x, E1.x);
    }
}

extern "C" void kernel_launch(void* const* d_in, const int* in_sizes, int n_in,
                              void* d_out, int out_size, void* d_ws, size_t ws_size,
                              hipStream_t stream) {
    const float* x  = (const float*)d_in[0];
    const float* cw = (const float*)d_in[1];
    const float* cb = (const float*)d_in[2];
    const float* th = (const float*)d_in[3];
    float* out = (float*)d_out;
    int B = in_sizes[0] / 196;                 // 4096, divisible by EPB
    qcnn_closed4<<<B / EPB, THREADS, 0, stream>>>(x, cw, cb, th, out, B);
}